// Round 4
// baseline (108.779 us; speedup 1.0000x reference)
//
#include <hip/hip_runtime.h>
#include <hip/hip_bf16.h>

typedef __bf16 bf16x8 __attribute__((ext_vector_type(8)));
typedef float f32x4 __attribute__((ext_vector_type(4)));

#define B_    8
#define NTOK  4096
#define CIN   512
#define COUT  512
#define SDIM  512
#define EPSF  1e-8f

// ---------------------------------------------------------------------------
// K1: m[b][i] = style[b,:] . mod_w[i,:] + mod_b[i] + 1    (one wave per output)
// ---------------------------------------------------------------------------
__global__ __launch_bounds__(256) void k_stylefc(
    const float* __restrict__ style, const float* __restrict__ mod_w,
    const float* __restrict__ mod_b, float* __restrict__ m_out) {
  int gw   = (blockIdx.x * 256 + threadIdx.x) >> 6;  // 0..4095
  int lane = threadIdx.x & 63;
  int b = gw >> 9;
  int i = gw & 511;
  const float* srow = style + (size_t)b * SDIM;
  const float* wrow = mod_w + (size_t)i * SDIM;
  float acc = 0.f;
#pragma unroll
  for (int k = 0; k < SDIM; k += 64) acc += srow[k + lane] * wrow[k + lane];
#pragma unroll
  for (int off = 32; off; off >>= 1) acc += __shfl_xor(acc, off, 64);
  if (lane == 0) m_out[b * CIN + i] = acc + mod_b[i] + 1.0f;
}

// ---------------------------------------------------------------------------
// K2 (fused): per output-channel o (one block each):
//  - demod[b][o] = rsqrt( sum_k (weight[k][o]*m[b][k])^2 + eps ),  8 b
//  - wimg: pre-swizzled bf16 W image, per k-tile kt (32 k):
//      byte(kt, o, k) = kt*32768 + o*64 + ((s ^ ((o>>1)&3))<<4) + (k&7)*2
//      where s = (k&31)>>3.  GEMM copies this LINEARLY into LDS; the swizzled
//      ds_read then lands 2-way/bank (free).
// ---------------------------------------------------------------------------
__global__ __launch_bounds__(256) void k_wprep(
    const float* __restrict__ weight, const float* __restrict__ m_buf,
    __bf16* __restrict__ wimg, float* __restrict__ demod) {
  int o = blockIdx.x;
  int tid = threadIdx.x;
  int wid = tid >> 6, lane = tid & 63;
  float acc[B_] = {0.f, 0.f, 0.f, 0.f, 0.f, 0.f, 0.f, 0.f};
#pragma unroll
  for (int rep = 0; rep < 2; ++rep) {
    int k = tid + rep * 256;
    float w = weight[(size_t)k * COUT + o];
    int kt = k >> 5, kl = k & 31, s = kl >> 3, ko = kl & 7;
    int sl = s ^ ((o >> 1) & 3);
    *(__bf16*)((char*)wimg + (size_t)kt * 32768 + o * 64 + sl * 16 + ko * 2) =
        (__bf16)w;
#pragma unroll
    for (int b = 0; b < B_; ++b) {
      float wm = w * m_buf[b * CIN + k];
      acc[b] += wm * wm;
    }
  }
  __shared__ float red[4][B_];
#pragma unroll
  for (int b = 0; b < B_; ++b) {
    float v = acc[b];
#pragma unroll
    for (int off = 32; off; off >>= 1) v += __shfl_xor(v, off, 64);
    if (lane == 0) red[wid][b] = v;
  }
  __syncthreads();
  if (tid < B_) {
    float s = red[0][tid] + red[1][tid] + red[2][tid] + red[3][tid];
    demod[tid * COUT + o] = rsqrtf(s + EPSF);
  }
}

// ---------------------------------------------------------------------------
// async global->LDS: dest = wave-uniform LDS base (+lane*16 by HW), src per-lane
// ---------------------------------------------------------------------------
__device__ __forceinline__ void async_copy16(void* lds_dst, const void* gsrc) {
  __builtin_amdgcn_global_load_lds(
      (const __attribute__((address_space(1))) unsigned int*)gsrc,
      (__attribute__((address_space(3))) unsigned int*)lds_dst, 16, 0, 0);
}

// ---------------------------------------------------------------------------
// K3: out[b,t,o] = demod[b][o] * sum_k (x[b,t,k]*m[b][k]) * W[k][o]
// Block tile: 64 tokens x 512 cols (FULL N) -> x read exactly once (no 4x
// LLC amplification).  512 thr = 8 waves, wave-tile 64x64 (wid = col group).
// mfma(W_frag, X_frag): W from LDS (swizzled image, gload_lds-staged, dbuf),
// X loaded DIRECTLY global->reg (32B/lane contiguous) with f32->*m->bf16 cvt.
// D: col(lane&15)=token, row((lane>>4)*4+j)=o  -> float4 epilogue stores.
// ---------------------------------------------------------------------------
__global__ __launch_bounds__(512) void k_gemm(
    const float* __restrict__ x, const __bf16* __restrict__ wimg,
    const float* __restrict__ m_buf, const float* __restrict__ demod,
    float* __restrict__ out) {
  int bid = blockIdx.x;         // 512 blocks = 8 b * 64 token-blocks
  int b   = bid >> 6;
  int tb  = bid & 63;

  __shared__ uint4 lds_u4[4096];  // 64 KiB: W0 | W1 (32 KiB each)
  char* W0 = (char*)lds_u4;
  char* W1 = (char*)lds_u4 + 32768;

  int tid  = threadIdx.x;
  int wid  = tid >> 6, lane = tid & 63;
  int ln15 = lane & 15, s = lane >> 4;

  f32x4 acc[4][4] = {};  // [mm: o-frag][nn: token-frag]

  const float* xb   = x + (size_t)(b * NTOK + tb * 64) * CIN;
  const float* mrow = m_buf + b * CIN;
  const char*  isrc = (const char*)wimg;

  auto issueW = [&](int kt, char* Wb) {
    const char* src = isrc + (size_t)kt * 32768;
#pragma unroll
    for (int q = 0; q < 4; ++q) {
      int off = (q * 8 + wid) * 1024;
      async_copy16(Wb + off, src + off + lane * 16);
    }
  };

  issueW(0, W0);
  __syncthreads();

#pragma unroll
  for (int kt = 0; kt < 16; ++kt) {
    char* Wc = (kt & 1) ? W1 : W0;
    char* Wn = (kt & 1) ? W0 : W1;
    // W fragments (A-operand): lane holds W[o0+mm*16+ln15][k-slot s]
    bf16x8 wf[4];
#pragma unroll
    for (int mm = 0; mm < 4; ++mm) {
      int r = wid * 64 + mm * 16 + ln15;
      wf[mm] = *(const bf16x8*)(Wc + r * 64 + ((s ^ ((r >> 1) & 3)) << 4));
    }
    if (kt < 15) issueW(kt + 1, Wn);

    const float* mk = mrow + kt * 32 + s * 8;
    float4 mv0 = *(const float4*)mk;
    float4 mv1 = *(const float4*)(mk + 4);
#pragma unroll
    for (int nn = 0; nn < 4; ++nn) {
      const float* px = xb + (size_t)(nn * 16 + ln15) * CIN + kt * 32 + s * 8;
      float4 a0 = *(const float4*)px;
      float4 a1 = *(const float4*)(px + 4);
      bf16x8 xf;
      xf[0] = (__bf16)(a0.x * mv0.x);
      xf[1] = (__bf16)(a0.y * mv0.y);
      xf[2] = (__bf16)(a0.z * mv0.z);
      xf[3] = (__bf16)(a0.w * mv0.w);
      xf[4] = (__bf16)(a1.x * mv1.x);
      xf[5] = (__bf16)(a1.y * mv1.y);
      xf[6] = (__bf16)(a1.z * mv1.z);
      xf[7] = (__bf16)(a1.w * mv1.w);
#pragma unroll
      for (int mm = 0; mm < 4; ++mm)
        acc[mm][nn] = __builtin_amdgcn_mfma_f32_16x16x32_bf16(
            wf[mm], xf, acc[mm][nn], 0, 0, 0);
    }
    if (kt < 15) __syncthreads();
  }

  // ---- epilogue: out[t][o..o+3] = acc * demod, float4 stores ----
  float* ob = out + (size_t)(b * NTOK + tb * 64) * COUT;
#pragma unroll
  for (int mm = 0; mm < 4; ++mm) {
    int o = wid * 64 + mm * 16 + s * 4;
    float4 dv = *(const float4*)(demod + b * COUT + o);
#pragma unroll
    for (int nn = 0; nn < 4; ++nn) {
      int t = nn * 16 + ln15;
      f32x4 r;
      r[0] = acc[mm][nn][0] * dv.x;
      r[1] = acc[mm][nn][1] * dv.y;
      r[2] = acc[mm][nn][2] * dv.z;
      r[3] = acc[mm][nn][3] * dv.w;
      *(f32x4*)(ob + (size_t)t * COUT + o) = r;
    }
  }
}

// ---------------------------------------------------------------------------
extern "C" void kernel_launch(void* const* d_in, const int* in_sizes, int n_in,
                              void* d_out, int out_size, void* d_ws, size_t ws_size,
                              hipStream_t stream) {
  const float* x      = (const float*)d_in[0];  // (8,4096,512)
  const float* style  = (const float*)d_in[1];  // (8,512)
  const float* weight = (const float*)d_in[2];  // (1,512,512)
  const float* mod_w  = (const float*)d_in[3];  // (512,512)
  const float* mod_b  = (const float*)d_in[4];  // (512,)
  float* out = (float*)d_out;

  // ws: m[8*512] f32 (16KB) | demod[8*512] f32 (16KB) | wimg 512KB
  float*  m_buf = (float*)d_ws;
  float*  demod = m_buf + B_ * CIN;
  __bf16* wimg  = (__bf16*)((char*)d_ws + 2 * B_ * CIN * sizeof(float));

  k_stylefc<<<dim3((B_ * CIN) / 4), dim3(256), 0, stream>>>(style, mod_w, mod_b, m_buf);
  k_wprep<<<dim3(COUT), dim3(256), 0, stream>>>(weight, m_buf, wimg, demod);
  k_gemm<<<dim3(8 * 64), dim3(512), 0, stream>>>(x, wimg, m_buf, demod, out);
}

// Round 5
// 54.071 us; speedup vs baseline: 2.0118x; 2.0118x over previous
//
#include <hip/hip_runtime.h>
#include <hip/hip_bf16.h>

typedef __bf16 bf16x8 __attribute__((ext_vector_type(8)));
typedef float f32x4 __attribute__((ext_vector_type(4)));

#define B_    8
#define NTOK  4096
#define CIN   512
#define COUT  512
#define SDIM  512
#define EPSF  1e-8f

// ---------------------------------------------------------------------------
// K1: m[b][i] = style[b,:] . mod_w[i,:] + mod_b[i] + 1    (one wave per output)
// ---------------------------------------------------------------------------
__global__ __launch_bounds__(256) void k_stylefc(
    const float* __restrict__ style, const float* __restrict__ mod_w,
    const float* __restrict__ mod_b, float* __restrict__ m_out) {
  int gw   = (blockIdx.x * 256 + threadIdx.x) >> 6;  // 0..4095
  int lane = threadIdx.x & 63;
  int b = gw >> 9;
  int i = gw & 511;
  const float* srow = style + (size_t)b * SDIM;
  const float* wrow = mod_w + (size_t)i * SDIM;
  float acc = 0.f;
#pragma unroll
  for (int k = 0; k < SDIM; k += 64) acc += srow[k + lane] * wrow[k + lane];
#pragma unroll
  for (int off = 32; off; off >>= 1) acc += __shfl_xor(acc, off, 64);
  if (lane == 0) m_out[b * CIN + i] = acc + mod_b[i] + 1.0f;
}

// ---------------------------------------------------------------------------
// K2 (fused): per output-channel o (one block each):
//  - demod[b][o] = rsqrt( sum_k (weight[k][o]*m[b][k])^2 + eps ),  8 b
//  - wimg: pre-swizzled bf16 W image for the GEMM.
//    Layout: [nb(2)][kt(16)][ tile 256 rows x 64B ]:
//      byte = nb*262144 + kt*16384 + row*64 + slot*16 + (k&7)*2
//      slot = ((k&31)>>3) ^ ((row>>1)&3)       (row = o&255, nb = o>>8)
//    GEMM stages each 16KB tile LINEARLY via global_load_lds; swizzled
//    ds_read_b128 then lands 2-way/bank (free).
// ---------------------------------------------------------------------------
__global__ __launch_bounds__(256) void k_wprep(
    const float* __restrict__ weight, const float* __restrict__ m_buf,
    __bf16* __restrict__ wimg, float* __restrict__ demod) {
  int o = blockIdx.x;
  int tid = threadIdx.x;
  int wid = tid >> 6, lane = tid & 63;
  int nb = o >> 8, row = o & 255;
  float acc[B_] = {0.f, 0.f, 0.f, 0.f, 0.f, 0.f, 0.f, 0.f};
#pragma unroll
  for (int rep = 0; rep < 2; ++rep) {
    int k = tid + rep * 256;
    float w = weight[(size_t)k * COUT + o];
    int kt = k >> 5, kl = k & 31, s = kl >> 3, ko = kl & 7;
    int sl = s ^ ((row >> 1) & 3);
    *(__bf16*)((char*)wimg + (size_t)nb * 262144 + kt * 16384 + row * 64 +
               sl * 16 + ko * 2) = (__bf16)w;
#pragma unroll
    for (int b = 0; b < B_; ++b) {
      float wm = w * m_buf[b * CIN + k];
      acc[b] += wm * wm;
    }
  }
  __shared__ float red[4][B_];
#pragma unroll
  for (int b = 0; b < B_; ++b) {
    float v = acc[b];
#pragma unroll
    for (int off = 32; off; off >>= 1) v += __shfl_xor(v, off, 64);
    if (lane == 0) red[wid][b] = v;
  }
  __syncthreads();
  if (tid < B_) {
    float s = red[0][tid] + red[1][tid] + red[2][tid] + red[3][tid];
    demod[tid * COUT + o] = rsqrtf(s + EPSF);
  }
}

// ---------------------------------------------------------------------------
// async global->LDS: dest = wave-uniform LDS base (+lane*16 by HW), src per-lane
// ---------------------------------------------------------------------------
__device__ __forceinline__ void async_copy16(void* lds_dst, const void* gsrc) {
  __builtin_amdgcn_global_load_lds(
      (const __attribute__((address_space(1))) unsigned int*)gsrc,
      (__attribute__((address_space(3))) unsigned int*)lds_dst, 16, 0, 0);
}

// ---------------------------------------------------------------------------
// K3: out[b,t,o] = demod[b][o] * sum_k (x[b,t,k]*m[b][k]) * W[k][o]
// Tile 64 tok x 256 col, 256 thr / 4 waves (wave-tile 64x64), BK=32, 16 kt.
// X: global->reg prefetch (issue at loop top), *m, bf16 cvt, XOR-swizzled
//    4KB LDS tile (dbuf).  x read ~once (2 nb-blocks of a panel share an XCD).
// W: async global_load_lds from pre-swizzled L2-resident image (dbuf, linear).
// mfma(W_frag, X_frag): D col = token, row = o  -> float4 epilogue stores.
// 1 barrier per kt.
// ---------------------------------------------------------------------------
__global__ __launch_bounds__(256) void k_gemm(
    const float* __restrict__ x, const __bf16* __restrict__ wimg,
    const float* __restrict__ m_buf, const float* __restrict__ demod,
    float* __restrict__ out) {
  // 1024 blocks; pair (nb=0,1) of one x-panel on the same XCD
  int bid = blockIdx.x;
  int xcd = bid & 7;
  int idx = bid >> 3;                 // 0..127
  int panel = xcd * 64 + (idx >> 1);  // 0..511
  int nb = idx & 1;
  int b = panel >> 6, tb = panel & 63;

  // LDS 40KB: X0 X1 (4KB: 64 rows x 64B) | W0 W1 (16KB: 256 rows x 64B)
  __shared__ uint4 lds_u4[2560];
  char* X0  = (char*)lds_u4;
  char* X1  = X0 + 4096;
  char* Wl0 = X0 + 8192;
  char* Wl1 = X0 + 24576;

  int tid = threadIdx.x;
  int wid = tid >> 6, lane = tid & 63;
  int ln15 = lane & 15, s = lane >> 4;

  f32x4 acc[4][4] = {};  // [mm: o-frag][nn: token-frag]

  const float* xb   = x + (size_t)(b * NTOK + tb * 64) * CIN;
  const float* mrow = m_buf + b * CIN;
  const char*  isrc = (const char*)wimg + (size_t)nb * 262144;

  // X staging map: thread -> (tok = tid>>2, kseg = tid&3 : 8 f32 = 32B)
  int xtok = tid >> 2, xseg = tid & 3;
  const float* xrow = xb + (size_t)xtok * CIN + xseg * 8;
  int xoff = xtok * 64 + ((xseg ^ ((xtok >> 1) & 3)) << 4);

  float4 xa0, xa1, mv0, mv1;
  auto loadX = [&](int kt) {
    const float* p = xrow + kt * 32;
    xa0 = *(const float4*)p;
    xa1 = *(const float4*)(p + 4);
    const float* mp = mrow + kt * 32 + xseg * 8;
    mv0 = *(const float4*)mp;
    mv1 = *(const float4*)(mp + 4);
  };
  auto writeX = [&](char* Xb) {
    bf16x8 hv;
    hv[0] = (__bf16)(xa0.x * mv0.x);
    hv[1] = (__bf16)(xa0.y * mv0.y);
    hv[2] = (__bf16)(xa0.z * mv0.z);
    hv[3] = (__bf16)(xa0.w * mv0.w);
    hv[4] = (__bf16)(xa1.x * mv1.x);
    hv[5] = (__bf16)(xa1.y * mv1.y);
    hv[6] = (__bf16)(xa1.z * mv1.z);
    hv[7] = (__bf16)(xa1.w * mv1.w);
    *(bf16x8*)(Xb + xoff) = hv;
  };
  auto issueW = [&](int kt, char* Wb) {
    const char* src = isrc + (size_t)kt * 16384;
#pragma unroll
    for (int q = 0; q < 4; ++q) {
      int off = (q * 4 + wid) * 1024;
      async_copy16(Wb + off, src + off + lane * 16);
    }
  };
  auto mmaStep = [&](const char* Xb, const char* Wb) {
    bf16x8 wf[4], xf[4];
#pragma unroll
    for (int mm = 0; mm < 4; ++mm) {
      int r = wid * 64 + mm * 16 + ln15;
      wf[mm] = *(const bf16x8*)(Wb + r * 64 + ((s ^ ((r >> 1) & 3)) << 4));
    }
#pragma unroll
    for (int nn = 0; nn < 4; ++nn) {
      int t = nn * 16 + ln15;
      xf[nn] = *(const bf16x8*)(Xb + t * 64 + ((s ^ ((t >> 1) & 3)) << 4));
    }
#pragma unroll
    for (int mm = 0; mm < 4; ++mm)
#pragma unroll
      for (int nn = 0; nn < 4; ++nn)
        acc[mm][nn] = __builtin_amdgcn_mfma_f32_16x16x32_bf16(
            wf[mm], xf[nn], acc[mm][nn], 0, 0, 0);
  };

  // prologue
  loadX(0);
  issueW(0, Wl0);
  writeX(X0);
  __syncthreads();

  // steady state: 1 barrier per kt
#pragma unroll
  for (int kt = 0; kt < 15; ++kt) {
    char* Xc = (kt & 1) ? X1 : X0;
    char* Wc = (kt & 1) ? Wl1 : Wl0;
    char* Xn = (kt & 1) ? X0 : X1;
    char* Wn = (kt & 1) ? Wl0 : Wl1;
    loadX(kt + 1);        // global->reg, latency hidden under MFMA
    issueW(kt + 1, Wn);   // async direct-to-LDS, drained by barrier
    mmaStep(Xc, Wc);
    writeX(Xn);           // auto s_waitcnt on xa, then LDS write (other buf)
    __syncthreads();
  }
  mmaStep(X1, Wl1);       // kt = 15

  // ---- epilogue: out[t][o..o+3] = acc * demod, float4 stores ----
  float* ob = out + (size_t)(b * NTOK + tb * 64) * COUT;
  int ocol = nb * 256 + wid * 64;
#pragma unroll
  for (int mm = 0; mm < 4; ++mm) {
    int o = ocol + mm * 16 + s * 4;
    float4 dv = *(const float4*)(demod + b * COUT + o);
#pragma unroll
    for (int nn = 0; nn < 4; ++nn) {
      int t = nn * 16 + ln15;
      f32x4 r;
      r[0] = acc[mm][nn][0] * dv.x;
      r[1] = acc[mm][nn][1] * dv.y;
      r[2] = acc[mm][nn][2] * dv.z;
      r[3] = acc[mm][nn][3] * dv.w;
      *(f32x4*)(ob + (size_t)t * COUT + o) = r;
    }
  }
}

// ---------------------------------------------------------------------------
extern "C" void kernel_launch(void* const* d_in, const int* in_sizes, int n_in,
                              void* d_out, int out_size, void* d_ws, size_t ws_size,
                              hipStream_t stream) {
  const float* x      = (const float*)d_in[0];  // (8,4096,512)
  const float* style  = (const float*)d_in[1];  // (8,512)
  const float* weight = (const float*)d_in[2];  // (1,512,512)
  const float* mod_w  = (const float*)d_in[3];  // (512,512)
  const float* mod_b  = (const float*)d_in[4];  // (512,)
  float* out = (float*)d_out;

  // ws: m[8*512] f32 (16KB) | demod[8*512] f32 (16KB) | wimg 512KB
  float*  m_buf = (float*)d_ws;
  float*  demod = m_buf + B_ * CIN;
  __bf16* wimg  = (__bf16*)((char*)d_ws + 2 * B_ * CIN * sizeof(float));

  k_stylefc<<<dim3((B_ * CIN) / 4), dim3(256), 0, stream>>>(style, mod_w, mod_b, m_buf);
  k_wprep<<<dim3(COUT), dim3(256), 0, stream>>>(weight, m_buf, wimg, demod);
  k_gemm<<<dim3(8 * 64 * 2), dim3(256), 0, stream>>>(x, wimg, m_buf, demod, out);
}